// Round 5
// baseline (476.297 us; speedup 1.0000x reference)
//
#include <hip/hip_runtime.h>
#include <stdint.h>

#define BATCH 8
#define MPTS 500000
#define NPTS (BATCH * MPTS)            // 4,000,000
#define NBQ 1024                       // 8 batches * (4*4*8) sub-blocks of 32x32x16
#define TP 8192                        // points per tile (srt = 32 KB)
#define NTILE ((NPTS + TP - 1) / TP)   // 489
#define HROW (NBQ + 1)                 // offsets row stride (last entry = tile cnt)
// flattened interface elements per batch: 96*512 (i) + 96*512 (j) + 112*1024 (k)
#define FEL1 49152
#define FEL2 98304
#define FELT 212992

template <int NT>
__device__ __forceinline__ void block_reduce2(float& tv, float& mse) {
    for (int off = 32; off > 0; off >>= 1) {
        tv  += __shfl_down(tv, off, 64);
        mse += __shfl_down(mse, off, 64);
    }
    __shared__ float stv[NT / 64], sms[NT / 64];
    int w = threadIdx.x >> 6, lane = threadIdx.x & 63;
    if (lane == 0) { stv[w] = tv; sms[w] = mse; }
    __syncthreads();
    if (threadIdx.x == 0) {
        float a = 0.f, m = 0.f;
        #pragma unroll
        for (int e = 0; e < NT / 64; ++e) { a += stv[e]; m += sms[e]; }
        tv = a; mse = m;
    }
}

// aux = (q:10 | l:14); sub-block 32x32x16. aux < 2^24 -> 0xFFFFFFFF safe sentinel.
__device__ __forceinline__ uint32_t pack_aux(int b, int i, int j, int k) {
    uint32_t q = ((uint32_t)b << 7) | ((uint32_t)(i >> 5) << 5) |
                 ((uint32_t)(j >> 5) << 3) | (uint32_t)(k >> 4);
    uint32_t l = ((uint32_t)(i & 31) << 9) | ((uint32_t)(j & 31) << 4) | (uint32_t)(k & 15);
    return (q << 14) | l;
}

// LDS bank swizzle: line s = il*32+jl holds 16 dwords; group-of-4 index XORed
// with (s>>1) so wave-wide b128 reads spread across all 32 banks.
__device__ __forceinline__ int gaddr(int s, int kl) {
    return s * 16 + (kl & 3) + ((((kl >> 2) ^ (s >> 1)) & 3) << 2);
}
__device__ __forceinline__ int goff(int s, int c) {
    return ((c ^ (s >> 1)) & 3) << 2;
}

// round float bits to top-16 (sign+exp+7man), round-half-up
__device__ __forceinline__ uint32_t val16(float f) {
    return (__float_as_uint(f) + 0x8000u) >> 16;
}
__device__ __forceinline__ float f16up(uint16_t u) {
    return __uint_as_float(((uint32_t)u) << 16);
}

// K1: fused per-tile hist + local exclusive scan + LDS counting sort + coalesced
// writeout. Record = (val16 << 16) | local14 (bits 14-15 zero).
// Block 0 also zeroes the per-batch completion counters (stream order makes
// them visible to accum_k).
__global__ void __launch_bounds__(1024, 8) sort_k(const int* __restrict__ idx,
                                                  const float* __restrict__ val,
                                                  uint16_t* __restrict__ hoff,
                                                  uint32_t* __restrict__ rec,
                                                  uint32_t* __restrict__ cnt8) {
    __shared__ uint32_t h[NBQ];     // counts -> placement cursors
    __shared__ uint32_t wtot[16];
    __shared__ uint32_t srt[TP];    // sorted packed records (32 KB)
    int tile = blockIdx.x;
    if (tile == 0 && threadIdx.x < BATCH) cnt8[threadIdx.x] = 0u;
    int p0 = tile * TP;
    int cnt = min(TP, NPTS - p0);   // always a multiple of 4
    h[threadIdx.x] = 0;
    __syncthreads();
    // phase 1: vectorized loads (4 points = 3 int4 + 1 float4), LDS histogram.
    uint32_t a[8]; uint32_t vpk[4];
    int ng = cnt >> 2;
    #pragma unroll
    for (int e = 0; e < 2; ++e) {
        int g = threadIdx.x + e * 1024;
        if (g < ng) {
            int p = p0 + g * 4;
            const int4* ip = (const int4*)(idx + (size_t)p * 3);
            int4 A = ip[0], B = ip[1], C = ip[2];
            float4 V = *(const float4*)(val + p);
            int b = p / MPTS;       // groups of 4 never straddle a batch
            a[4*e+0] = pack_aux(b, A.x, A.y, A.z);
            a[4*e+1] = pack_aux(b, A.w, B.x, B.y);
            a[4*e+2] = pack_aux(b, B.z, B.w, C.x);
            a[4*e+3] = pack_aux(b, C.y, C.z, C.w);
            vpk[2*e]     = val16(V.x) | (val16(V.y) << 16);
            vpk[2*e + 1] = val16(V.z) | (val16(V.w) << 16);
            #pragma unroll
            for (int u = 0; u < 4; ++u) atomicAdd(&h[a[4*e+u] >> 14], 1u);
        } else {
            a[4*e+0] = a[4*e+1] = a[4*e+2] = a[4*e+3] = 0xFFFFFFFFu;
            vpk[2*e] = vpk[2*e + 1] = 0u;
        }
    }
    __syncthreads();
    // phase 2: block exclusive scan of 1024 counts (wave shuffles, 2 barriers)
    int q = threadIdx.x, lane = q & 63, wave = q >> 6;
    uint32_t cq = h[q];
    uint32_t inc = cq;
    #pragma unroll
    for (int off = 1; off < 64; off <<= 1) {
        uint32_t n = __shfl_up(inc, off, 64);
        if (lane >= off) inc += n;
    }
    if (lane == 63) wtot[wave] = inc;
    __syncthreads();
    if (q < 16) {
        uint32_t w = wtot[q];
        #pragma unroll
        for (int off = 1; off < 16; off <<= 1) {
            uint32_t n = __shfl_up(w, off, 16);
            if (q >= off) w += n;
        }
        wtot[q] = w;
    }
    __syncthreads();
    uint32_t lstart = (wave ? wtot[wave - 1] : 0u) + inc - cq;
    hoff[(size_t)tile * HROW + q] = (uint16_t)lstart;   // tile-local start offset
    if (q == 0) hoff[(size_t)tile * HROW + NBQ] = (uint16_t)cnt;
    h[q] = lstart;                                      // placement cursor
    __syncthreads();
    // phase 3: place into LDS sorted order
    #pragma unroll
    for (int e = 0; e < 8; ++e) {
        if (a[e] != 0xFFFFFFFFu) {
            uint32_t qq = a[e] >> 14;
            uint32_t u = (vpk[e >> 1] >> ((e & 1) * 16)) & 0xFFFFu;
            srt[atomicAdd(&h[qq], 1u)] = (u << 16) | (a[e] & 16383u);
        }
    }
    __syncthreads();
    // phase 4: fully coalesced linear writeout (uint4)
    uint4* recq = (uint4*)(rec + (size_t)tile * TP);
    const uint4* sr4 = (const uint4*)srt;
    for (int s = threadIdx.x; s < (cnt >> 2); s += 1024) recq[s] = sr4[s];
}

// K2: per-bucket LDS accumulate + interior stencil + faces + per-batch ticket.
// XCD-chunked qb swizzle (batch = blockIdx&7). After faces/pa are written and
// fenced, thread 0 takes a ticket on cnt8[batch]; the 128th finisher runs that
// batch's boundary interfaces + final reduction (faces are L2-local to this
// XCD under the swizzle, and this overlaps other batches' accumulation).
// No block ever waits -> safe under any dispatch order (G16).
__global__ void __launch_bounds__(1024, 8) accum_k(const uint32_t* __restrict__ rec,
                                                   const uint16_t* __restrict__ hoff,
                                                   uint16_t* __restrict__ faces,
                                                   float2* __restrict__ pa,
                                                   uint32_t* __restrict__ cnt8,
                                                   float* __restrict__ out) {
    __shared__ float g[16384];   // voxel (s = il*32+jl, kl) at gaddr(s,kl)
    __shared__ uint16_t sA[NTILE], sB[NTILE];
    __shared__ uint32_t slast;
    int qb = ((blockIdx.x & 7) << 7) | (blockIdx.x >> 3);   // bijective, batch-per-XCD
    int b = qb >> 7;
    // prefetch hoff columns qb, qb+1 (978 scattered 2B loads, one parallel burst)
    if (threadIdx.x < NTILE) {
        const uint16_t* row = hoff + (size_t)threadIdx.x * HROW + qb;
        sA[threadIdx.x] = row[0];
        sB[threadIdx.x] = row[1];
    }
    {
        float4 z = make_float4(0.f, 0.f, 0.f, 0.f);
        #pragma unroll
        for (int c = 0; c < 4; ++c)
            *(float4*)&g[(threadIdx.x + c * 1024) * 4] = z;
    }
    __syncthreads();
    {
        int grp = threadIdx.x >> 3;      // 0..127
        int r8  = threadIdx.x & 7;
        for (int t = grp; t < NTILE; t += 128) {
            uint32_t a0 = sA[t], a1 = sB[t];
            const uint32_t* rp = rec + (size_t)t * TP;
            for (uint32_t r = a0 + r8; r < a1; r += 8) {
                uint32_t e = rp[r];
                int l = e & 16383;
                atomicAdd(&g[gaddr(l >> 4, l & 15)], __uint_as_float(e & 0xFFFF0000u));
            }
        }
    }
    __syncthreads();
    // stencil: thread t owns line s = t (il = t>>5, jl = t&31)
    float tv = 0.f, mse = 0.f;
    {
        int s = threadIdx.x;
        int jl = s & 31, il = s >> 5;
        bool jin = jl < 31, iin = il < 31;
        float own[16];
        #pragma unroll
        for (int c = 0; c < 4; ++c)
            *(float4*)&own[c * 4] = *(const float4*)&g[s * 16 + goff(s, c)];
        #pragma unroll
        for (int k = 0; k < 15; ++k) {
            float d = own[k + 1] - own[k]; tv += fabsf(d); mse += d * d;
        }
        #pragma unroll
        for (int hh = 0; hh < 2; ++hh) {
            if (jin) {
                float jn[8];
                *(float4*)&jn[0] = *(const float4*)&g[(s + 1) * 16 + goff(s + 1, 2 * hh)];
                *(float4*)&jn[4] = *(const float4*)&g[(s + 1) * 16 + goff(s + 1, 2 * hh + 1)];
                #pragma unroll
                for (int k = 0; k < 8; ++k) {
                    float d = jn[k] - own[8 * hh + k]; tv += fabsf(d); mse += d * d;
                }
            }
            if (iin) {
                float inb[8];
                *(float4*)&inb[0] = *(const float4*)&g[(s + 32) * 16 + goff(s + 32, 2 * hh)];
                *(float4*)&inb[4] = *(const float4*)&g[(s + 32) * 16 + goff(s + 32, 2 * hh + 1)];
                #pragma unroll
                for (int k = 0; k < 8; ++k) {
                    float d = inb[k] - own[8 * hh + k]; tv += fabsf(d); mse += d * d;
                }
            }
        }
    }
    // faces (ushort = top-16 float bits): layout as before
    {
        uint16_t* f = faces + (size_t)qb * 4096;
        int t = threadIdx.x;
        if (t < 512) {
            int hi = t >> 4, lo = t & 15;
            f[t]        = (uint16_t)(__float_as_uint(g[gaddr(hi, lo)]) >> 16);
            f[512 + t]  = (uint16_t)(__float_as_uint(g[gaddr(992 + hi, lo)]) >> 16);
            f[1024 + t] = (uint16_t)(__float_as_uint(g[gaddr(hi * 32, lo)]) >> 16);
            f[1536 + t] = (uint16_t)(__float_as_uint(g[gaddr(hi * 32 + 31, lo)]) >> 16);
        }
        f[2048 + t] = (uint16_t)(__float_as_uint(g[gaddr(t, 0)]) >> 16);
        f[3072 + t] = (uint16_t)(__float_as_uint(g[gaddr(t, 15)]) >> 16);
    }
    block_reduce2<1024>(tv, mse);
    if (threadIdx.x == 0) pa[qb] = make_float2(tv, mse);
    // ---- per-batch completion ticket (release: fence all threads, then bar) --
    __threadfence();
    __syncthreads();
    if (threadIdx.x == 0) slast = atomicAdd(&cnt8[b], 1u);
    __syncthreads();
    if (slast == 127u) {
        __threadfence();   // acquire side: all 128 blocks' faces/pa visible
        float tv2 = 0.f, mse2 = 0.f;
        for (int i = threadIdx.x; i < NBQ / BATCH; i += 1024) {
            float2 v = pa[b * (NBQ / BATCH) + i]; tv2 += v.x; mse2 += v.y;
        }
        // flattened interface sweep: f -> (axis, r, e), coalesced per face row
        for (int f = threadIdx.x; f < FELT; f += 1024) {
            int qA, qB, fA, fB, e;
            if (f < FEL1) {                     // axis i
                int r = f >> 9; e = f & 511;
                int s = r >> 5, u = (r >> 3) & 3, w = r & 7;
                qA = (b << 7) | (s << 5) | (u << 3) | w; qB = qA + 32;
                fA = 512; fB = 0;
            } else if (f < FEL2) {              // axis j
                int f2 = f - FEL1;
                int r = f2 >> 9; e = f2 & 511;
                int s = r >> 5, u = (r >> 3) & 3, w = r & 7;
                qA = (b << 7) | (u << 5) | (s << 3) | w; qB = qA + 8;
                fA = 1536; fB = 1024;
            } else {                            // axis k
                int f2 = f - FEL2;
                int r = f2 >> 10; e = f2 & 1023;
                int s = r >> 4, u = (r >> 2) & 3, v = r & 3;
                qA = (b << 7) | (u << 5) | (v << 3) | s; qB = qA + 1;
                fA = 3072; fB = 2048;
            }
            float d = f16up(faces[(size_t)qB * 4096 + fB + e]) -
                      f16up(faces[(size_t)qA * 4096 + fA + e]);
            tv2 += fabsf(d); mse2 += d * d;
        }
        block_reduce2<1024>(tv2, mse2);
        if (threadIdx.x == 0) {
            out[b]     = tv2  * (1.f / 2097152.f);  // / X^3
            out[8 + b] = mse2 * (1.f / 32512.f);    // / (2X^2-2X)
        }
    }
}

extern "C" void kernel_launch(void* const* d_in, const int* in_sizes, int n_in,
                              void* d_out, int out_size, void* d_ws, size_t ws_size,
                              hipStream_t stream) {
    const int*   indices = (const int*)d_in[0];   // (B, M, 3) int32
    const float* values  = (const float*)d_in[1]; // (B, M) float32
    float*       out     = (float*)d_out;         // (2, B) float32

    // workspace (~25 MiB), 256B-aligned sections
    char* wp = (char*)d_ws;
    uint16_t* hoff  = (uint16_t*)wp;                           // NTILE*HROW u16 (1.0 MB)
    wp += (((size_t)NTILE * HROW * 2) + 255) & ~(size_t)255;
    float2*   pa    = (float2*)wp;                             // NBQ        (8 KB)
    wp += (NBQ * 8 + 255) & ~(size_t)255;
    uint32_t* cnt8  = (uint32_t*)wp;                           // BATCH tickets
    wp += (BATCH * 4 + 255) & ~(size_t)255;
    uint32_t* rec   = (uint32_t*)wp;                           // NTILE*TP   (16 MB)
    wp += (((size_t)NTILE * TP * 4) + 255) & ~(size_t)255;
    uint16_t* faces = (uint16_t*)wp;                           // NBQ*4096   (8 MB)

    sort_k <<<NTILE, 1024, 0, stream>>>(indices, values, hoff, rec, cnt8);
    accum_k<<<NBQ,   1024, 0, stream>>>(rec, hoff, faces, pa, cnt8, out);
}

// Round 6
// 218.682 us; speedup vs baseline: 2.1780x; 2.1780x over previous
//
#include <hip/hip_runtime.h>
#include <stdint.h>

#define BATCH 8
#define MPTS 500000
#define NPTS (BATCH * MPTS)            // 4,000,000
#define NBQ 1024                       // 8 batches * (4*4*8) sub-blocks of 32x32x16
#define TP 8192                        // points per tile (srt = 32 KB)
#define NTILE ((NPTS + TP - 1) / TP)   // 489
#define HROW (NBQ + 1)                 // offsets row stride (last entry = tile cnt)
// flattened interface elements per batch: 96*512 (i) + 96*512 (j) + 112*1024 (k)
#define FEL1 49152
#define FEL2 98304
#define FELT 212992

template <int NT>
__device__ __forceinline__ void block_reduce2(float& tv, float& mse) {
    for (int off = 32; off > 0; off >>= 1) {
        tv  += __shfl_down(tv, off, 64);
        mse += __shfl_down(mse, off, 64);
    }
    __shared__ float stv[NT / 64], sms[NT / 64];
    int w = threadIdx.x >> 6, lane = threadIdx.x & 63;
    if (lane == 0) { stv[w] = tv; sms[w] = mse; }
    __syncthreads();
    if (threadIdx.x == 0) {
        float a = 0.f, m = 0.f;
        #pragma unroll
        for (int e = 0; e < NT / 64; ++e) { a += stv[e]; m += sms[e]; }
        tv = a; mse = m;
    }
}

// aux = (q:10 | l:14); sub-block 32x32x16. aux < 2^24 -> 0xFFFFFFFF safe sentinel.
__device__ __forceinline__ uint32_t pack_aux(int b, int i, int j, int k) {
    uint32_t q = ((uint32_t)b << 7) | ((uint32_t)(i >> 5) << 5) |
                 ((uint32_t)(j >> 5) << 3) | (uint32_t)(k >> 4);
    uint32_t l = ((uint32_t)(i & 31) << 9) | ((uint32_t)(j & 31) << 4) | (uint32_t)(k & 15);
    return (q << 14) | l;
}

// LDS bank swizzle: line s = il*32+jl holds 16 dwords; group-of-4 index XORed
// with (s>>1) so wave-wide b128 reads spread across all 32 banks.
__device__ __forceinline__ int gaddr(int s, int kl) {
    return s * 16 + (kl & 3) + ((((kl >> 2) ^ (s >> 1)) & 3) << 2);
}
__device__ __forceinline__ int goff(int s, int c) {
    return ((c ^ (s >> 1)) & 3) << 2;
}

// round float bits to top-16 (sign+exp+7man), round-half-up
__device__ __forceinline__ uint32_t val16(float f) {
    return (__float_as_uint(f) + 0x8000u) >> 16;
}
__device__ __forceinline__ float f16up(uint16_t u) {
    return __uint_as_float(((uint32_t)u) << 16);
}

// K1: fused per-tile hist + local exclusive scan + LDS counting sort + coalesced
// writeout. Record = (val16 << 16) | local14 (bits 14-15 zero).
__global__ void __launch_bounds__(1024, 8) sort_k(const int* __restrict__ idx,
                                                  const float* __restrict__ val,
                                                  uint16_t* __restrict__ hoff,
                                                  uint32_t* __restrict__ rec) {
    __shared__ uint32_t h[NBQ];     // counts -> placement cursors
    __shared__ uint32_t wtot[16];
    __shared__ uint32_t srt[TP];    // sorted packed records (32 KB)
    int tile = blockIdx.x;
    int p0 = tile * TP;
    int cnt = min(TP, NPTS - p0);   // always a multiple of 4
    h[threadIdx.x] = 0;
    __syncthreads();
    // phase 1: vectorized loads (4 points = 3 int4 + 1 float4), LDS histogram.
    uint32_t a[8]; uint32_t vpk[4];
    int ng = cnt >> 2;
    #pragma unroll
    for (int e = 0; e < 2; ++e) {
        int g = threadIdx.x + e * 1024;
        if (g < ng) {
            int p = p0 + g * 4;
            const int4* ip = (const int4*)(idx + (size_t)p * 3);
            int4 A = ip[0], B = ip[1], C = ip[2];
            float4 V = *(const float4*)(val + p);
            int b = p / MPTS;       // groups of 4 never straddle a batch
            a[4*e+0] = pack_aux(b, A.x, A.y, A.z);
            a[4*e+1] = pack_aux(b, A.w, B.x, B.y);
            a[4*e+2] = pack_aux(b, B.z, B.w, C.x);
            a[4*e+3] = pack_aux(b, C.y, C.z, C.w);
            vpk[2*e]     = val16(V.x) | (val16(V.y) << 16);
            vpk[2*e + 1] = val16(V.z) | (val16(V.w) << 16);
            #pragma unroll
            for (int u = 0; u < 4; ++u) atomicAdd(&h[a[4*e+u] >> 14], 1u);
        } else {
            a[4*e+0] = a[4*e+1] = a[4*e+2] = a[4*e+3] = 0xFFFFFFFFu;
            vpk[2*e] = vpk[2*e + 1] = 0u;
        }
    }
    __syncthreads();
    // phase 2: block exclusive scan of 1024 counts (wave shuffles, 2 barriers)
    int q = threadIdx.x, lane = q & 63, wave = q >> 6;
    uint32_t cq = h[q];
    uint32_t inc = cq;
    #pragma unroll
    for (int off = 1; off < 64; off <<= 1) {
        uint32_t n = __shfl_up(inc, off, 64);
        if (lane >= off) inc += n;
    }
    if (lane == 63) wtot[wave] = inc;
    __syncthreads();
    if (q < 16) {
        uint32_t w = wtot[q];
        #pragma unroll
        for (int off = 1; off < 16; off <<= 1) {
            uint32_t n = __shfl_up(w, off, 16);
            if (q >= off) w += n;
        }
        wtot[q] = w;
    }
    __syncthreads();
    uint32_t lstart = (wave ? wtot[wave - 1] : 0u) + inc - cq;
    hoff[(size_t)tile * HROW + q] = (uint16_t)lstart;   // tile-local start offset
    if (q == 0) hoff[(size_t)tile * HROW + NBQ] = (uint16_t)cnt;
    h[q] = lstart;                                      // placement cursor
    __syncthreads();
    // phase 3: place into LDS sorted order
    #pragma unroll
    for (int e = 0; e < 8; ++e) {
        if (a[e] != 0xFFFFFFFFu) {
            uint32_t qq = a[e] >> 14;
            uint32_t u = (vpk[e >> 1] >> ((e & 1) * 16)) & 0xFFFFu;
            srt[atomicAdd(&h[qq], 1u)] = (u << 16) | (a[e] & 16383u);
        }
    }
    __syncthreads();
    // phase 4: fully coalesced linear writeout (uint4)
    uint4* recq = (uint4*)(rec + (size_t)tile * TP);
    const uint4* sr4 = (const uint4*)srt;
    for (int s = threadIdx.x; s < (cnt >> 2); s += 1024) recq[s] = sr4[s];
}

// K2: per-bucket LDS accumulate. XCD-chunked qb swizzle (batch = blockIdx&7):
// each XCD's blocks read one batch's contiguous ~2 MB of rec -> L2-resident.
// hoff columns prefetched to LDS in one burst before the zero-init.
// NO device fences here (round-5 lesson: per-wave __threadfence on multi-XCD
// CDNA = L2 wb/inv storm, +350 us).
__global__ void __launch_bounds__(1024, 8) accum_k(const uint32_t* __restrict__ rec,
                                                   const uint16_t* __restrict__ hoff,
                                                   uint16_t* __restrict__ faces,
                                                   float2* __restrict__ pa) {
    __shared__ float g[16384];   // voxel (s = il*32+jl, kl) at gaddr(s,kl)
    __shared__ uint16_t sA[NTILE], sB[NTILE];
    int qb = ((blockIdx.x & 7) << 7) | (blockIdx.x >> 3);   // bijective, batch-per-XCD
    // prefetch hoff columns qb, qb+1 (978 scattered 2B loads, one parallel burst)
    if (threadIdx.x < NTILE) {
        const uint16_t* row = hoff + (size_t)threadIdx.x * HROW + qb;
        sA[threadIdx.x] = row[0];
        sB[threadIdx.x] = row[1];
    }
    {
        float4 z = make_float4(0.f, 0.f, 0.f, 0.f);
        #pragma unroll
        for (int c = 0; c < 4; ++c)
            *(float4*)&g[(threadIdx.x + c * 1024) * 4] = z;
    }
    __syncthreads();
    {
        int grp = threadIdx.x >> 3;      // 0..127
        int r8  = threadIdx.x & 7;
        for (int t = grp; t < NTILE; t += 128) {
            uint32_t a0 = sA[t], a1 = sB[t];
            const uint32_t* rp = rec + (size_t)t * TP;
            for (uint32_t r = a0 + r8; r < a1; r += 8) {
                uint32_t e = rp[r];
                int l = e & 16383;
                atomicAdd(&g[gaddr(l >> 4, l & 15)], __uint_as_float(e & 0xFFFF0000u));
            }
        }
    }
    __syncthreads();
    // stencil: thread t owns line s = t (il = t>>5, jl = t&31)
    float tv = 0.f, mse = 0.f;
    {
        int s = threadIdx.x;
        int jl = s & 31, il = s >> 5;
        bool jin = jl < 31, iin = il < 31;
        float own[16];
        #pragma unroll
        for (int c = 0; c < 4; ++c)
            *(float4*)&own[c * 4] = *(const float4*)&g[s * 16 + goff(s, c)];
        #pragma unroll
        for (int k = 0; k < 15; ++k) {
            float d = own[k + 1] - own[k]; tv += fabsf(d); mse += d * d;
        }
        #pragma unroll
        for (int hh = 0; hh < 2; ++hh) {
            if (jin) {
                float jn[8];
                *(float4*)&jn[0] = *(const float4*)&g[(s + 1) * 16 + goff(s + 1, 2 * hh)];
                *(float4*)&jn[4] = *(const float4*)&g[(s + 1) * 16 + goff(s + 1, 2 * hh + 1)];
                #pragma unroll
                for (int k = 0; k < 8; ++k) {
                    float d = jn[k] - own[8 * hh + k]; tv += fabsf(d); mse += d * d;
                }
            }
            if (iin) {
                float inb[8];
                *(float4*)&inb[0] = *(const float4*)&g[(s + 32) * 16 + goff(s + 32, 2 * hh)];
                *(float4*)&inb[4] = *(const float4*)&g[(s + 32) * 16 + goff(s + 32, 2 * hh + 1)];
                #pragma unroll
                for (int k = 0; k < 8; ++k) {
                    float d = inb[k] - own[8 * hh + k]; tv += fabsf(d); mse += d * d;
                }
            }
        }
    }
    // faces (ushort = top-16 float bits): layout as before
    {
        uint16_t* f = faces + (size_t)qb * 4096;
        int t = threadIdx.x;
        if (t < 512) {
            int hi = t >> 4, lo = t & 15;
            f[t]        = (uint16_t)(__float_as_uint(g[gaddr(hi, lo)]) >> 16);
            f[512 + t]  = (uint16_t)(__float_as_uint(g[gaddr(992 + hi, lo)]) >> 16);
            f[1024 + t] = (uint16_t)(__float_as_uint(g[gaddr(hi * 32, lo)]) >> 16);
            f[1536 + t] = (uint16_t)(__float_as_uint(g[gaddr(hi * 32 + 31, lo)]) >> 16);
        }
        f[2048 + t] = (uint16_t)(__float_as_uint(g[gaddr(t, 0)]) >> 16);
        f[3072 + t] = (uint16_t)(__float_as_uint(g[gaddr(t, 15)]) >> 16);
    }
    block_reduce2<1024>(tv, mse);
    if (threadIdx.x == 0) pa[qb] = make_float2(tv, mse);
}

// K3: merged boundary + final. One block per batch (1024 threads): interior
// partials from pa, then the flattened per-batch interface sweep (round-5
// phase-C code, numerics verified absmax 0.0). Faces of batch b are L2-local
// to one XCD under accum_k's swizzle.
__global__ void __launch_bounds__(1024) bf_k(const uint16_t* __restrict__ faces,
                                             const float2* __restrict__ pa,
                                             float* __restrict__ out) {
    int b = blockIdx.x;
    float tv = 0.f, mse = 0.f;
    for (int i = threadIdx.x; i < NBQ / BATCH; i += 1024) {
        float2 v = pa[b * (NBQ / BATCH) + i]; tv += v.x; mse += v.y;
    }
    for (int f = threadIdx.x; f < FELT; f += 1024) {
        int qA, qB, fA, fB, e;
        if (f < FEL1) {                     // axis i
            int r = f >> 9; e = f & 511;
            int s = r >> 5, u = (r >> 3) & 3, w = r & 7;
            qA = (b << 7) | (s << 5) | (u << 3) | w; qB = qA + 32;
            fA = 512; fB = 0;
        } else if (f < FEL2) {              // axis j
            int f2 = f - FEL1;
            int r = f2 >> 9; e = f2 & 511;
            int s = r >> 5, u = (r >> 3) & 3, w = r & 7;
            qA = (b << 7) | (u << 5) | (s << 3) | w; qB = qA + 8;
            fA = 1536; fB = 1024;
        } else {                            // axis k
            int f2 = f - FEL2;
            int r = f2 >> 10; e = f2 & 1023;
            int s = r >> 4, u = (r >> 2) & 3, v = r & 3;
            qA = (b << 7) | (u << 5) | (v << 3) | s; qB = qA + 1;
            fA = 3072; fB = 2048;
        }
        float d = f16up(faces[(size_t)qB * 4096 + fB + e]) -
                  f16up(faces[(size_t)qA * 4096 + fA + e]);
        tv += fabsf(d); mse += d * d;
    }
    block_reduce2<1024>(tv, mse);
    if (threadIdx.x == 0) {
        out[b]     = tv  * (1.f / 2097152.f);   // / X^3
        out[8 + b] = mse * (1.f / 32512.f);     // / (2X^2-2X)
    }
}

extern "C" void kernel_launch(void* const* d_in, const int* in_sizes, int n_in,
                              void* d_out, int out_size, void* d_ws, size_t ws_size,
                              hipStream_t stream) {
    const int*   indices = (const int*)d_in[0];   // (B, M, 3) int32
    const float* values  = (const float*)d_in[1]; // (B, M) float32
    float*       out     = (float*)d_out;         // (2, B) float32

    // workspace (~25 MiB), 256B-aligned sections
    char* wp = (char*)d_ws;
    uint16_t* hoff  = (uint16_t*)wp;                           // NTILE*HROW u16 (1.0 MB)
    wp += (((size_t)NTILE * HROW * 2) + 255) & ~(size_t)255;
    float2*   pa    = (float2*)wp;                             // NBQ        (8 KB)
    wp += (NBQ * 8 + 255) & ~(size_t)255;
    uint32_t* rec   = (uint32_t*)wp;                           // NTILE*TP   (16 MB)
    wp += (((size_t)NTILE * TP * 4) + 255) & ~(size_t)255;
    uint16_t* faces = (uint16_t*)wp;                           // NBQ*4096   (8 MB)

    sort_k <<<NTILE, 1024, 0, stream>>>(indices, values, hoff, rec);
    accum_k<<<NBQ,   1024, 0, stream>>>(rec, hoff, faces, pa);
    bf_k   <<<BATCH, 1024, 0, stream>>>(faces, pa, out);
}